// Round 3
// baseline (390.411 us; speedup 1.0000x reference)
//
#include <hip/hip_runtime.h>
#include <hip/hip_bf16.h>

#define AS1 __attribute__((address_space(1)))
#define AS3 __attribute__((address_space(3)))

typedef __hip_bfloat16 bf16;
typedef short bf16x8 __attribute__((ext_vector_type(8)));
typedef float f32x4 __attribute__((ext_vector_type(4)));

static constexpr int D = 1024, S = 2048, NB = 4, NH = 16, DK = 64;
static constexpr int M = NB * S;  // 8192

__device__ __forceinline__ void gload16(void* lds_dst, const void* gsrc) {
  __builtin_amdgcn_global_load_lds((const AS1 void*)gsrc, (AS3 void*)lds_dst, 16, 0, 0);
}

// ---------------- fp32 -> bf16 convert ----------------
__global__ void cvt_bf16_kernel(const float* __restrict__ src, bf16* __restrict__ dst, int n) {
  int i = (blockIdx.x * blockDim.x + threadIdx.x) * 4;
  int stride = gridDim.x * blockDim.x * 4;
  for (; i < n; i += stride) {
    float4 v = *(const float4*)(src + i);
    union { bf16 h[4]; uint2 u; } t;
    t.h[0] = __float2bfloat16(v.x);
    t.h[1] = __float2bfloat16(v.y);
    t.h[2] = __float2bfloat16(v.z);
    t.h[3] = __float2bfloat16(v.w);
    *(uint2*)(dst + i) = t.u;
  }
}

// ---------------- NT GEMM: C[m,n] = sum_k A[m,k]*Bw[n,k] ----------------
// MODE 0: write bf16 to [B,H,S,64] layout (proj for Q/K), scaled
// MODE 1: write bf16 to Vt [B,H,64,S] layout (A=Wv, B=x)
// MODE 2: write fp32 row-major [M,N] (final output projection)
template <int MODE>
__global__ __launch_bounds__(256)
void gemm_bt(const bf16* __restrict__ A, const bf16* __restrict__ Bw,
             void* __restrict__ out, int K, int ldc, float scale) {
  __shared__ __align__(16) char lds[32768];
  char* Asm = lds;
  char* Bsm = lds + 16384;
  const int tid = threadIdx.x;
  const int w = tid >> 6, l = tid & 63;
  const int ql = l & 15, g = l >> 4;
  const int rowA = blockIdx.x * 128;
  const int rowB = blockIdx.y * 128;
  const int wr = (w >> 1) * 64, wc = (w & 1) * 64;

  f32x4 acc[4][4] = {};

  for (int k0 = 0; k0 < K; k0 += 64) {
#pragma unroll
    for (int i = 0; i < 4; ++i) {
      int o = ((i * 4 + w) << 10) + (l << 4);
      int row = o >> 7;
      int u = ((o >> 4) & 7) ^ (row & 7);
      gload16(Asm + ((i * 4 + w) << 10), A + (size_t)(rowA + row) * K + k0 + (u << 3));
      gload16(Bsm + ((i * 4 + w) << 10), Bw + (size_t)(rowB + row) * K + k0 + (u << 3));
    }
    __syncthreads();
#pragma unroll
    for (int kk = 0; kk < 2; ++kk) {
      bf16x8 af[4], bfr[4];
#pragma unroll
      for (int m = 0; m < 4; ++m) {
        int row = wr + m * 16 + ql;
        int sub = ((kk << 2) + g) ^ (row & 7);
        af[m] = *(const bf16x8*)(Asm + row * 128 + sub * 16);
      }
#pragma unroll
      for (int n = 0; n < 4; ++n) {
        int row = wc + n * 16 + ql;
        int sub = ((kk << 2) + g) ^ (row & 7);
        bfr[n] = *(const bf16x8*)(Bsm + row * 128 + sub * 16);
      }
#pragma unroll
      for (int m = 0; m < 4; ++m)
#pragma unroll
        for (int n = 0; n < 4; ++n)
          acc[m][n] = __builtin_amdgcn_mfma_f32_16x16x32_bf16(af[m], bfr[n], acc[m][n], 0, 0, 0);
    }
    __syncthreads();
  }

#pragma unroll
  for (int m = 0; m < 4; ++m)
#pragma unroll
    for (int n = 0; n < 4; ++n)
#pragma unroll
      for (int r = 0; r < 4; ++r) {
        int gm = rowA + wr + m * 16 + g * 4 + r;
        int gn = rowB + wc + n * 16 + ql;
        float v = acc[m][n][r] * scale;
        if (MODE == 0) {
          int b = gm >> 11, s = gm & 2047, h = gn >> 6, d = gn & 63;
          ((bf16*)out)[(((size_t)(b * 16 + h) * S) + s) * DK + d] = __float2bfloat16(v);
        } else if (MODE == 1) {
          int b = gn >> 11, s = gn & 2047;
          ((bf16*)out)[((size_t)b * 1024 + gm) * S + s] = __float2bfloat16(v);
        } else {
          ((float*)out)[(size_t)gm * ldc + gn] = v;
        }
      }
}

// ---------------- causal flash attention ----------------
// grid: (S/128, B*H), 256 threads (4 waves x 32 q-rows)
// Q pre-scaled by 1/sqrt(dk). Q,K: [B,H,S,64]; Vt: [B,H,64,S]; O: [B,S,H*64]
__global__ __launch_bounds__(256)
void attn_kernel(const bf16* __restrict__ Q, const bf16* __restrict__ Km,
                 const bf16* __restrict__ Vt, bf16* __restrict__ O) {
  __shared__ __align__(16) char P[4][2][1024];
  const int tid = threadIdx.x;
  const int w = tid >> 6, l = tid & 63;
  const int ql = l & 15, g = l >> 4;
  const int bh = blockIdx.y;
  const int qbase = blockIdx.x * 128 + w * 32;
  const int sxor = (ql & 3) << 1;
  const float L2E = 1.44269504f;

  const bf16* Qb = Q + (size_t)bh * S * DK;
  const bf16* Kb = Km + (size_t)bh * S * DK;
  const bf16* Vb = Vt + (size_t)bh * DK * S;

  bf16x8 qf[2][2];
#pragma unroll
  for (int sub = 0; sub < 2; ++sub)
#pragma unroll
    for (int kk = 0; kk < 2; ++kk)
      qf[sub][kk] = *(const bf16x8*)(Qb + (size_t)(qbase + sub * 16 + ql) * DK + kk * 32 + g * 8);

  f32x4 oacc[2][4] = {};
  float mrow[2] = {-3e38f, -3e38f};
  float lrow[2] = {0.f, 0.f};

  const int kv_end = qbase + 32;
  for (int kv0 = 0; kv0 < kv_end; kv0 += 32) {
    bf16x8 kf[2][2];
#pragma unroll
    for (int mt = 0; mt < 2; ++mt)
#pragma unroll
      for (int kk = 0; kk < 2; ++kk)
        kf[mt][kk] = *(const bf16x8*)(Kb + (size_t)(kv0 + mt * 16 + ql) * DK + kk * 32 + g * 8);

    // scores^T[kv][q] via swapped operands
    f32x4 st[2][2];
#pragma unroll
    for (int sub = 0; sub < 2; ++sub)
#pragma unroll
      for (int mt = 0; mt < 2; ++mt) {
        f32x4 a = {0.f, 0.f, 0.f, 0.f};
        a = __builtin_amdgcn_mfma_f32_16x16x32_bf16(kf[mt][0], qf[sub][0], a, 0, 0, 0);
        a = __builtin_amdgcn_mfma_f32_16x16x32_bf16(kf[mt][1], qf[sub][1], a, 0, 0, 0);
        st[sub][mt] = a;
      }

#pragma unroll
    for (int sub = 0; sub < 2; ++sub) {
      const int qpos = qbase + sub * 16 + ql;
      if (kv0 + 31 > qbase + sub * 16) {
#pragma unroll
        for (int mt = 0; mt < 2; ++mt)
#pragma unroll
          for (int r = 0; r < 4; ++r) {
            int kvpos = kv0 + mt * 16 + g * 4 + r;
            if (kvpos > qpos) st[sub][mt][r] = -3e38f;
          }
      }
      float tmax = -3e38f;
#pragma unroll
      for (int mt = 0; mt < 2; ++mt)
#pragma unroll
        for (int r = 0; r < 4; ++r) tmax = fmaxf(tmax, st[sub][mt][r]);
      tmax = fmaxf(tmax, __shfl_xor(tmax, 16, 64));
      tmax = fmaxf(tmax, __shfl_xor(tmax, 32, 64));
      float mnew = fmaxf(mrow[sub], tmax);
      float sc = exp2f((mrow[sub] - mnew) * L2E);
      mrow[sub] = mnew;
      lrow[sub] *= sc;
      // BUGFIX: accumulator rows are q = g*4+r, but sc is for q = ql.
      // Broadcast the correct per-row rescale factor before applying.
#pragma unroll
      for (int r = 0; r < 4; ++r) {
        float scr = __shfl(sc, g * 4 + r, 16);
#pragma unroll
        for (int n = 0; n < 4; ++n) oacc[sub][n][r] *= scr;
      }

      float psum = 0.f;
#pragma unroll
      for (int mt = 0; mt < 2; ++mt) {
        union { ushort us[4]; uint2 u; } pk;
#pragma unroll
        for (int r = 0; r < 4; ++r) {
          float p = exp2f((st[sub][mt][r] - mnew) * L2E);
          psum += p;
          union { bf16 b; ushort u; } cv;
          cv.b = __float2bfloat16(p);
          pk.us[r] = cv.u;
        }
        *(uint2*)&P[w][sub][(ql << 6) + ((((mt << 2) + g) ^ sxor) << 3)] = pk.u;
      }
      psum += __shfl_xor(psum, 16, 64);
      psum += __shfl_xor(psum, 32, 64);
      lrow[sub] += psum;
    }

    // PV
    bf16x8 vf[4];
#pragma unroll
    for (int n = 0; n < 4; ++n)
      vf[n] = *(const bf16x8*)(Vb + (size_t)(n * 16 + ql) * S + kv0 + g * 8);
#pragma unroll
    for (int sub = 0; sub < 2; ++sub) {
      bf16x8 pa = *(const bf16x8*)&P[w][sub][(ql << 6) + (((g << 1) ^ sxor) << 3)];
#pragma unroll
      for (int n = 0; n < 4; ++n)
        oacc[sub][n] = __builtin_amdgcn_mfma_f32_16x16x32_bf16(pa, vf[n], oacc[sub][n], 0, 0, 0);
    }
  }

  const int bo = bh >> 4, hh = bh & 15;
  bf16* Ob = O + (size_t)bo * S * D + hh * 64;
#pragma unroll
  for (int sub = 0; sub < 2; ++sub) {
    float ldv[4];
#pragma unroll
    for (int r = 0; r < 4; ++r) ldv[r] = __shfl(lrow[sub], g * 4 + r, 16);
#pragma unroll
    for (int r = 0; r < 4; ++r) {
      int qpos = qbase + sub * 16 + g * 4 + r;
      float inv = 1.f / ldv[r];
#pragma unroll
      for (int n = 0; n < 4; ++n)
        Ob[(size_t)qpos * D + n * 16 + ql] = __float2bfloat16(oacc[sub][n][r] * inv);
    }
  }
}

extern "C" void kernel_launch(void* const* d_in, const int* in_sizes, int n_in,
                              void* d_out, int out_size, void* d_ws, size_t ws_size,
                              hipStream_t stream) {
  const float* x  = (const float*)d_in[0];
  const float* wq = (const float*)d_in[1];
  const float* wk = (const float*)d_in[2];
  const float* wv = (const float*)d_in[3];
  const float* wo = (const float*)d_in[4];

  char* ws = (char*)d_ws;
  bf16* xb  = (bf16*)(ws);                      // 16 MB  [8192,1024]
  bf16* wqb = (bf16*)(ws + (16u << 20));        // 2 MB
  bf16* wkb = (bf16*)(ws + (18u << 20));
  bf16* wvb = (bf16*)(ws + (20u << 20));
  bf16* wob = (bf16*)(ws + (22u << 20));
  bf16* Qb  = (bf16*)(ws + (24u << 20));        // 16 MB [B,H,S,64] (pre-scaled)
  bf16* Kb  = (bf16*)(ws + (40u << 20));        // 16 MB [B,H,S,64]
  bf16* Vtb = (bf16*)(ws + (56u << 20));        // 16 MB [B,H,64,S]
  bf16* Ob  = (bf16*)(ws + (72u << 20));        // 16 MB [8192,1024]

  cvt_bf16_kernel<<<2048, 256, 0, stream>>>(x, xb, M * D);
  cvt_bf16_kernel<<<1024, 256, 0, stream>>>(wq, wqb, D * D);
  cvt_bf16_kernel<<<1024, 256, 0, stream>>>(wk, wkb, D * D);
  cvt_bf16_kernel<<<1024, 256, 0, stream>>>(wv, wvb, D * D);
  cvt_bf16_kernel<<<1024, 256, 0, stream>>>(wo, wob, D * D);

  // Q = x Wq^T (scaled 1/8), K = x Wk^T  -> [B,H,S,64]
  gemm_bt<0><<<dim3(M / 128, D / 128), 256, 0, stream>>>(xb, wqb, Qb, D, D, 0.125f);
  gemm_bt<0><<<dim3(M / 128, D / 128), 256, 0, stream>>>(xb, wkb, Kb, D, D, 1.0f);
  // Vt = Wv x^T -> [B,H,64,S]
  gemm_bt<1><<<dim3(D / 128, M / 128), 256, 0, stream>>>(wvb, xb, Vtb, D, D, 1.0f);

  attn_kernel<<<dim3(S / 128, NB * NH), 256, 0, stream>>>(Qb, Kb, Vtb, Ob);

  // out = O Wo^T (fp32)
  gemm_bt<2><<<dim3(M / 128, D / 128), 256, 0, stream>>>(Ob, wob, d_out, D, D, 1.0f);
}

// Round 5
// 281.728 us; speedup vs baseline: 1.3858x; 1.3858x over previous
//
#include <hip/hip_runtime.h>
#include <hip/hip_bf16.h>

#define AS1 __attribute__((address_space(1)))
#define AS3 __attribute__((address_space(3)))

typedef __hip_bfloat16 bf16;
typedef short bf16x8 __attribute__((ext_vector_type(8)));
typedef float f32x4 __attribute__((ext_vector_type(4)));

static constexpr int D = 1024, S = 2048, NB = 4, NH = 16, DK = 64;
static constexpr int M = NB * S;  // 8192

__device__ __forceinline__ void gload16(void* lds_dst, const void* gsrc) {
  __builtin_amdgcn_global_load_lds((const AS1 void*)gsrc, (AS3 void*)lds_dst, 16, 0, 0);
}

// ---------------- fp32 -> bf16 convert ----------------
__global__ void cvt_bf16_kernel(const float* __restrict__ src, bf16* __restrict__ dst, int n) {
  int i = (blockIdx.x * blockDim.x + threadIdx.x) * 4;
  int stride = gridDim.x * blockDim.x * 4;
  for (; i < n; i += stride) {
    float4 v = *(const float4*)(src + i);
    union { bf16 h[4]; uint2 u; } t;
    t.h[0] = __float2bfloat16(v.x);
    t.h[1] = __float2bfloat16(v.y);
    t.h[2] = __float2bfloat16(v.z);
    t.h[3] = __float2bfloat16(v.w);
    *(uint2*)(dst + i) = t.u;
  }
}

// ---------------- NT GEMM: C[m,n] = sum_k A[m,k]*Bw[n,k] ----------------
template <int MODE>
__global__ __launch_bounds__(256)
void gemm_bt(const bf16* __restrict__ A, const bf16* __restrict__ Bw,
             void* __restrict__ out, int K, int ldc, float scale) {
  __shared__ __align__(16) char lds[32768];
  char* Asm = lds;
  char* Bsm = lds + 16384;
  const int tid = threadIdx.x;
  const int w = tid >> 6, l = tid & 63;
  const int ql = l & 15, g = l >> 4;
  const int rowA = blockIdx.x * 128;
  const int rowB = blockIdx.y * 128;
  const int wr = (w >> 1) * 64, wc = (w & 1) * 64;

  f32x4 acc[4][4] = {};

  for (int k0 = 0; k0 < K; k0 += 64) {
#pragma unroll
    for (int i = 0; i < 4; ++i) {
      int o = ((i * 4 + w) << 10) + (l << 4);
      int row = o >> 7;
      int u = ((o >> 4) & 7) ^ (row & 7);
      gload16(Asm + ((i * 4 + w) << 10), A + (size_t)(rowA + row) * K + k0 + (u << 3));
      gload16(Bsm + ((i * 4 + w) << 10), Bw + (size_t)(rowB + row) * K + k0 + (u << 3));
    }
    __syncthreads();
#pragma unroll
    for (int kk = 0; kk < 2; ++kk) {
      bf16x8 af[4], bfr[4];
#pragma unroll
      for (int m = 0; m < 4; ++m) {
        int row = wr + m * 16 + ql;
        int sub = ((kk << 2) + g) ^ (row & 7);
        af[m] = *(const bf16x8*)(Asm + row * 128 + sub * 16);
      }
#pragma unroll
      for (int n = 0; n < 4; ++n) {
        int row = wc + n * 16 + ql;
        int sub = ((kk << 2) + g) ^ (row & 7);
        bfr[n] = *(const bf16x8*)(Bsm + row * 128 + sub * 16);
      }
#pragma unroll
      for (int m = 0; m < 4; ++m)
#pragma unroll
        for (int n = 0; n < 4; ++n)
          acc[m][n] = __builtin_amdgcn_mfma_f32_16x16x32_bf16(af[m], bfr[n], acc[m][n], 0, 0, 0);
    }
    __syncthreads();
  }

#pragma unroll
  for (int m = 0; m < 4; ++m)
#pragma unroll
    for (int n = 0; n < 4; ++n)
#pragma unroll
      for (int r = 0; r < 4; ++r) {
        int gm = rowA + wr + m * 16 + g * 4 + r;
        int gn = rowB + wc + n * 16 + ql;
        float v = acc[m][n][r] * scale;
        if (MODE == 0) {
          int b = gm >> 11, s = gm & 2047, h = gn >> 6, d = gn & 63;
          ((bf16*)out)[(((size_t)(b * 16 + h) * S) + s) * DK + d] = __float2bfloat16(v);
        } else if (MODE == 1) {
          int b = gn >> 11, s = gn & 2047;
          ((bf16*)out)[((size_t)b * 1024 + gm) * S + s] = __float2bfloat16(v);
        } else {
          ((float*)out)[(size_t)gm * ldc + gn] = v;
        }
      }
}

// ---------------- causal flash attention (v2) ----------------
// grid: (16, B*H), 256 threads = 4 waves. Wave w handles q-strip (x + 16w)
// of 32 rows (load-balanced). KVBLK=64. Q pre-scaled.
// Q,K: [B,H,S,64]; Vt: [B,H,64,S]; O: [B,S,H*64]
__global__ __launch_bounds__(256)
void attn_kernel(const bf16* __restrict__ Q, const bf16* __restrict__ Km,
                 const bf16* __restrict__ Vt, bf16* __restrict__ O) {
  // per-wave per-sub P tile: [16 q-rows][64 kv] bf16, XOR-swizzled rows
  __shared__ __align__(16) char P[4][2][2048];
  const int tid = threadIdx.x;
  const int w = tid >> 6, l = tid & 63;
  const int ql = l & 15, g = l >> 4;
  const int bh = blockIdx.y;
  const int sidx = blockIdx.x + 16 * w;   // 0..63, balanced across blocks
  const int qbase = sidx * 32;
  const int swz = (ql & 7) << 4;
  const float L2E = 1.44269504f;

  const bf16* Qb = Q + (size_t)bh * S * DK;
  const bf16* Kb = Km + (size_t)bh * S * DK;
  const bf16* Vb = Vt + (size_t)bh * DK * S;

  bf16x8 qf[2][2];
#pragma unroll
  for (int sub = 0; sub < 2; ++sub)
#pragma unroll
    for (int kk = 0; kk < 2; ++kk)
      qf[sub][kk] = *(const bf16x8*)(Qb + (size_t)(qbase + sub * 16 + ql) * DK + kk * 32 + g * 8);

  f32x4 oacc[2][4] = {};
  float mrow[2] = {-3e38f, -3e38f};
  float lrow[2] = {0.f, 0.f};

  const int kv_end = qbase + 32;
  for (int kv0 = 0; kv0 < kv_end; kv0 += 64) {
    const bool last = (kv0 + 64 >= kv_end);

    // ---- QK^T: st[sub][mt] = scores^T for 64 kv x 32 q ----
    f32x4 st[2][4];
#pragma unroll
    for (int sub = 0; sub < 2; ++sub)
#pragma unroll
      for (int mt = 0; mt < 4; ++mt) st[sub][mt] = f32x4{0.f, 0.f, 0.f, 0.f};
#pragma unroll
    for (int kk = 0; kk < 2; ++kk) {
      bf16x8 kf[4];
#pragma unroll
      for (int mt = 0; mt < 4; ++mt)
        kf[mt] = *(const bf16x8*)(Kb + (size_t)(kv0 + mt * 16 + ql) * DK + kk * 32 + g * 8);
#pragma unroll
      for (int sub = 0; sub < 2; ++sub)
#pragma unroll
        for (int mt = 0; mt < 4; ++mt)
          st[sub][mt] = __builtin_amdgcn_mfma_f32_16x16x32_bf16(kf[mt], qf[sub][kk], st[sub][mt], 0, 0, 0);
    }

    // ---- hoist V loads: latency hides under softmax ----
    bf16x8 vf[2][4];
#pragma unroll
    for (int kk = 0; kk < 2; ++kk)
#pragma unroll
      for (int n = 0; n < 4; ++n)
        vf[kk][n] = *(const bf16x8*)(Vb + (size_t)(n * 16 + ql) * S + kv0 + kk * 32 + g * 8);

    // ---- online softmax per sub (16 q rows; lane owns q = ql column) ----
#pragma unroll
    for (int sub = 0; sub < 2; ++sub) {
      const int qpos = qbase + sub * 16 + ql;
      if (last) {
#pragma unroll
        for (int mt = 0; mt < 4; ++mt)
#pragma unroll
          for (int r = 0; r < 4; ++r) {
            int kvpos = kv0 + mt * 16 + g * 4 + r;
            if (kvpos > qpos) st[sub][mt][r] = -3e38f;
          }
      }
      float tmax = -3e38f;
#pragma unroll
      for (int mt = 0; mt < 4; ++mt)
#pragma unroll
        for (int r = 0; r < 4; ++r) tmax = fmaxf(tmax, st[sub][mt][r]);
      tmax = fmaxf(tmax, __shfl_xor(tmax, 16, 64));
      tmax = fmaxf(tmax, __shfl_xor(tmax, 32, 64));
      float mnew = fmaxf(mrow[sub], tmax);
      float sc = exp2f((mrow[sub] - mnew) * L2E);
      mrow[sub] = mnew;
      lrow[sub] *= sc;
      // accumulator rows are q = g*4+r; broadcast that row's rescale factor
#pragma unroll
      for (int r = 0; r < 4; ++r) {
        float scr = __shfl(sc, g * 4 + r, 16);
#pragma unroll
        for (int n = 0; n < 4; ++n) oacc[sub][n][r] *= scr;
      }

      float psum = 0.f;
#pragma unroll
      for (int mt = 0; mt < 4; ++mt) {
        union { ushort us[4]; uint2 u; } pk;
#pragma unroll
        for (int r = 0; r < 4; ++r) {
          float p = exp2f((st[sub][mt][r] - mnew) * L2E);
          psum += p;
          union { bf16 b; ushort u; } cv;
          cv.b = __float2bfloat16(p);
          pk.us[r] = cv.u;
        }
        // P[q=ql][kv=mt*16+g*4..+3] -> byte ql*128 + mt*32 + g*8, swizzled
        *(uint2*)&P[w][sub][((ql << 7) + (mt << 5) + (g << 3)) ^ swz] = pk.u;
      }
      psum += __shfl_xor(psum, 16, 64);
      psum += __shfl_xor(psum, 32, 64);
      lrow[sub] += psum;
    }

    // ---- PV: oacc += P(32x64) * V(64x64) ----
#pragma unroll
    for (int kk = 0; kk < 2; ++kk)
#pragma unroll
      for (int sub = 0; sub < 2; ++sub) {
        // A-frag: P[ql][kk*32 + g*8 ..+8] -> byte ql*128 + kk*64 + g*16, swizzled
        bf16x8 pa = *(const bf16x8*)&P[w][sub][((ql << 7) + (kk << 6) + (g << 4)) ^ swz];
#pragma unroll
        for (int n = 0; n < 4; ++n)
          oacc[sub][n] = __builtin_amdgcn_mfma_f32_16x16x32_bf16(pa, vf[kk][n], oacc[sub][n], 0, 0, 0);
      }
  }

  const int bo = bh >> 4, hh = bh & 15;
  bf16* Ob = O + (size_t)bo * S * D + hh * 64;
#pragma unroll
  for (int sub = 0; sub < 2; ++sub) {
    float ldv[4];
#pragma unroll
    for (int r = 0; r < 4; ++r) ldv[r] = __shfl(lrow[sub], g * 4 + r, 16);
#pragma unroll
    for (int r = 0; r < 4; ++r) {
      int qpos = qbase + sub * 16 + g * 4 + r;
      float inv = 1.f / ldv[r];
#pragma unroll
      for (int n = 0; n < 4; ++n)
        Ob[(size_t)qpos * D + n * 16 + ql] = __float2bfloat16(oacc[sub][n][r] * inv);
    }
  }
}

extern "C" void kernel_launch(void* const* d_in, const int* in_sizes, int n_in,
                              void* d_out, int out_size, void* d_ws, size_t ws_size,
                              hipStream_t stream) {
  const float* x  = (const float*)d_in[0];
  const float* wq = (const float*)d_in[1];
  const float* wk = (const float*)d_in[2];
  const float* wv = (const float*)d_in[3];
  const float* wo = (const float*)d_in[4];

  char* ws = (char*)d_ws;
  bf16* xb  = (bf16*)(ws);                      // 16 MB  [8192,1024]
  bf16* wqb = (bf16*)(ws + (16u << 20));        // 2 MB
  bf16* wkb = (bf16*)(ws + (18u << 20));
  bf16* wvb = (bf16*)(ws + (20u << 20));
  bf16* wob = (bf16*)(ws + (22u << 20));
  bf16* Qb  = (bf16*)(ws + (24u << 20));        // 16 MB [B,H,S,64] (pre-scaled)
  bf16* Kb  = (bf16*)(ws + (40u << 20));        // 16 MB [B,H,S,64]
  bf16* Vtb = (bf16*)(ws + (56u << 20));        // 16 MB [B,H,64,S]
  bf16* Ob  = (bf16*)(ws + (72u << 20));        // 16 MB [8192,1024]

  cvt_bf16_kernel<<<2048, 256, 0, stream>>>(x, xb, M * D);
  cvt_bf16_kernel<<<1024, 256, 0, stream>>>(wq, wqb, D * D);
  cvt_bf16_kernel<<<1024, 256, 0, stream>>>(wk, wkb, D * D);
  cvt_bf16_kernel<<<1024, 256, 0, stream>>>(wv, wvb, D * D);
  cvt_bf16_kernel<<<1024, 256, 0, stream>>>(wo, wob, D * D);

  // Q = x Wq^T (scaled 1/8), K = x Wk^T  -> [B,H,S,64]
  gemm_bt<0><<<dim3(M / 128, D / 128), 256, 0, stream>>>(xb, wqb, Qb, D, D, 0.125f);
  gemm_bt<0><<<dim3(M / 128, D / 128), 256, 0, stream>>>(xb, wkb, Kb, D, D, 1.0f);
  // Vt = Wv x^T -> [B,H,64,S]
  gemm_bt<1><<<dim3(D / 128, M / 128), 256, 0, stream>>>(wvb, xb, Vtb, D, D, 1.0f);

  attn_kernel<<<dim3(16, NB * NH), 256, 0, stream>>>(Qb, Kb, Vtb, Ob);

  // out = O Wo^T (fp32)
  gemm_bt<2><<<dim3(M / 128, D / 128), 256, 0, stream>>>(Ob, wob, d_out, D, D, 1.0f);
}

// Round 6
// 277.790 us; speedup vs baseline: 1.4054x; 1.0142x over previous
//
#include <hip/hip_runtime.h>
#include <hip/hip_bf16.h>

#define AS1 __attribute__((address_space(1)))
#define AS3 __attribute__((address_space(3)))

typedef __hip_bfloat16 bf16;
typedef short bf16x8 __attribute__((ext_vector_type(8)));
typedef float f32x4 __attribute__((ext_vector_type(4)));

static constexpr int D = 1024, S = 2048, NB = 4, NH = 16, DK = 64;
static constexpr int M = NB * S;  // 8192

__device__ __forceinline__ void gload16(void* lds_dst, const void* gsrc) {
  __builtin_amdgcn_global_load_lds((const AS1 void*)gsrc, (AS3 void*)lds_dst, 16, 0, 0);
}

// ---------------- fp32 -> bf16 convert ----------------
__global__ void cvt_bf16_kernel(const float* __restrict__ src, bf16* __restrict__ dst, int n) {
  int i = (blockIdx.x * blockDim.x + threadIdx.x) * 4;
  int stride = gridDim.x * blockDim.x * 4;
  for (; i < n; i += stride) {
    float4 v = *(const float4*)(src + i);
    union { bf16 h[4]; uint2 u; } t;
    t.h[0] = __float2bfloat16(v.x);
    t.h[1] = __float2bfloat16(v.y);
    t.h[2] = __float2bfloat16(v.z);
    t.h[3] = __float2bfloat16(v.w);
    *(uint2*)(dst + i) = t.u;
  }
}

// ---------------- NT GEMM: C[m,n] = sum_k A[m,k]*Bw[n,k] ----------------
template <int MODE>
__global__ __launch_bounds__(256)
void gemm_bt(const bf16* __restrict__ A, const bf16* __restrict__ Bw,
             void* __restrict__ out, int K, int ldc, float scale) {
  __shared__ __align__(16) char lds[32768];
  char* Asm = lds;
  char* Bsm = lds + 16384;
  const int tid = threadIdx.x;
  const int w = tid >> 6, l = tid & 63;
  const int ql = l & 15, g = l >> 4;
  const int rowA = blockIdx.x * 128;
  const int rowB = blockIdx.y * 128;
  const int wr = (w >> 1) * 64, wc = (w & 1) * 64;

  f32x4 acc[4][4] = {};

  for (int k0 = 0; k0 < K; k0 += 64) {
#pragma unroll
    for (int i = 0; i < 4; ++i) {
      int o = ((i * 4 + w) << 10) + (l << 4);
      int row = o >> 7;
      int u = ((o >> 4) & 7) ^ (row & 7);
      gload16(Asm + ((i * 4 + w) << 10), A + (size_t)(rowA + row) * K + k0 + (u << 3));
      gload16(Bsm + ((i * 4 + w) << 10), Bw + (size_t)(rowB + row) * K + k0 + (u << 3));
    }
    __syncthreads();
#pragma unroll
    for (int kk = 0; kk < 2; ++kk) {
      bf16x8 af[4], bfr[4];
#pragma unroll
      for (int m = 0; m < 4; ++m) {
        int row = wr + m * 16 + ql;
        int sub = ((kk << 2) + g) ^ (row & 7);
        af[m] = *(const bf16x8*)(Asm + row * 128 + sub * 16);
      }
#pragma unroll
      for (int n = 0; n < 4; ++n) {
        int row = wc + n * 16 + ql;
        int sub = ((kk << 2) + g) ^ (row & 7);
        bfr[n] = *(const bf16x8*)(Bsm + row * 128 + sub * 16);
      }
#pragma unroll
      for (int m = 0; m < 4; ++m)
#pragma unroll
        for (int n = 0; n < 4; ++n)
          acc[m][n] = __builtin_amdgcn_mfma_f32_16x16x32_bf16(af[m], bfr[n], acc[m][n], 0, 0, 0);
    }
    __syncthreads();
  }

#pragma unroll
  for (int m = 0; m < 4; ++m)
#pragma unroll
    for (int n = 0; n < 4; ++n)
#pragma unroll
      for (int r = 0; r < 4; ++r) {
        int gm = rowA + wr + m * 16 + g * 4 + r;
        int gn = rowB + wc + n * 16 + ql;
        float v = acc[m][n][r] * scale;
        if (MODE == 0) {
          int b = gm >> 11, s = gm & 2047, h = gn >> 6, d = gn & 63;
          ((bf16*)out)[(((size_t)(b * 16 + h) * S) + s) * DK + d] = __float2bfloat16(v);
        } else if (MODE == 1) {
          int b = gn >> 11, s = gn & 2047;
          ((bf16*)out)[((size_t)b * 1024 + gm) * S + s] = __float2bfloat16(v);
        } else {
          ((float*)out)[(size_t)gm * ldc + gn] = v;
        }
      }
}

// ---------------- causal flash attention (v3: defer-max, no per-tile shuffles) ----------------
// grid: (16, B*H), 256 threads = 4 waves. Wave w handles q-strip (x + 16w)
// of 32 rows (load-balanced). KVBLK=64. Q pre-scaled.
// Q,K: [B,H,S,64]; Vt: [B,H,64,S]; O: [B,S,H*64]
__global__ __launch_bounds__(256)
void attn_kernel(const bf16* __restrict__ Q, const bf16* __restrict__ Km,
                 const bf16* __restrict__ Vt, bf16* __restrict__ O) {
  // per-wave per-sub P tile: [16 q-rows][64 kv] bf16, XOR-swizzled rows
  __shared__ __align__(16) char P[4][2][2048];
  const int tid = threadIdx.x;
  const int w = tid >> 6, l = tid & 63;
  const int ql = l & 15, g = l >> 4;
  const int bh = blockIdx.y;
  const int sidx = blockIdx.x + 16 * w;   // 0..63, balanced across blocks
  const int qbase = sidx * 32;
  const int swz = (ql & 7) << 4;
  const float L2E = 1.44269504f;
  const float THR = 8.0f;   // defer-max threshold (T13)

  const bf16* Qb = Q + (size_t)bh * S * DK;
  const bf16* Kb = Km + (size_t)bh * S * DK;
  const bf16* Vb = Vt + (size_t)bh * DK * S;

  bf16x8 qf[2][2];
#pragma unroll
  for (int sub = 0; sub < 2; ++sub)
#pragma unroll
    for (int kk = 0; kk < 2; ++kk)
      qf[sub][kk] = *(const bf16x8*)(Qb + (size_t)(qbase + sub * 16 + ql) * DK + kk * 32 + g * 8);

  f32x4 oacc[2][4] = {};
  float mrow[2] = {-3e38f, -3e38f};   // running max for row q = ql (per lane)
  float lrow[2] = {0.f, 0.f};         // PER-LANE PARTIAL row sum (lane's kv slots only)

  const int kv_end = qbase + 32;
  for (int kv0 = 0; kv0 < kv_end; kv0 += 64) {
    const bool last = (kv0 + 64 >= kv_end);

    // ---- QK^T: st[sub][mt] = scores^T for 64 kv x 32 q ----
    f32x4 st[2][4];
#pragma unroll
    for (int sub = 0; sub < 2; ++sub)
#pragma unroll
      for (int mt = 0; mt < 4; ++mt) st[sub][mt] = f32x4{0.f, 0.f, 0.f, 0.f};
    __builtin_amdgcn_s_setprio(1);
#pragma unroll
    for (int kk = 0; kk < 2; ++kk) {
      bf16x8 kf[4];
#pragma unroll
      for (int mt = 0; mt < 4; ++mt)
        kf[mt] = *(const bf16x8*)(Kb + (size_t)(kv0 + mt * 16 + ql) * DK + kk * 32 + g * 8);
#pragma unroll
      for (int sub = 0; sub < 2; ++sub)
#pragma unroll
        for (int mt = 0; mt < 4; ++mt)
          st[sub][mt] = __builtin_amdgcn_mfma_f32_16x16x32_bf16(kf[mt], qf[sub][kk], st[sub][mt], 0, 0, 0);
    }
    __builtin_amdgcn_s_setprio(0);

    // ---- hoist V loads: latency hides under softmax ----
    bf16x8 vf[2][4];
#pragma unroll
    for (int kk = 0; kk < 2; ++kk)
#pragma unroll
      for (int n = 0; n < 4; ++n)
        vf[kk][n] = *(const bf16x8*)(Vb + (size_t)(n * 16 + ql) * S + kv0 + kk * 32 + g * 8);

    // ---- online softmax, defer-max: common path has ZERO cross-lane ops ----
#pragma unroll
    for (int sub = 0; sub < 2; ++sub) {
      const int qpos = qbase + sub * 16 + ql;
      if (last) {
#pragma unroll
        for (int mt = 0; mt < 4; ++mt)
#pragma unroll
          for (int r = 0; r < 4; ++r) {
            int kvpos = kv0 + mt * 16 + g * 4 + r;
            if (kvpos > qpos) st[sub][mt][r] = -3e38f;
          }
      }
      // in-lane partial max (lane's 16 kv slots of row ql)
      float tmax = st[sub][0][0];
#pragma unroll
      for (int mt = 0; mt < 4; ++mt)
#pragma unroll
        for (int r = 0; r < 4; ++r) tmax = fmaxf(tmax, st[sub][mt][r]);
      // trigger only when some lane's partial max exceeds mrow+THR
      if (__any(tmax > mrow[sub] + THR)) {
        float rm = tmax;
        rm = fmaxf(rm, __shfl_xor(rm, 16, 64));
        rm = fmaxf(rm, __shfl_xor(rm, 32, 64));   // row max across g groups
        float mnew = fmaxf(mrow[sub], rm);
        float sc = exp2f((mrow[sub] - mnew) * L2E);
        mrow[sub] = mnew;
        lrow[sub] *= sc;                           // lane-local partial, row ql
#pragma unroll
        for (int r = 0; r < 4; ++r) {              // acc rows are q = g*4+r
          float scr = __shfl(sc, g * 4 + r, 16);
#pragma unroll
          for (int n = 0; n < 4; ++n) oacc[sub][n][r] *= scr;
        }
      }

      float psum = 0.f;
#pragma unroll
      for (int mt = 0; mt < 4; ++mt) {
        union { ushort us[4]; uint2 u; } pk;
#pragma unroll
        for (int r = 0; r < 4; ++r) {
          float p = exp2f((st[sub][mt][r] - mrow[sub]) * L2E);  // bounded by e^THR
          psum += p;
          union { bf16 b; ushort u; } cv;
          cv.b = __float2bfloat16(p);
          pk.us[r] = cv.u;
        }
        // P[q=ql][kv=mt*16+g*4..+3] -> byte ql*128 + mt*32 + g*8, swizzled
        *(uint2*)&P[w][sub][((ql << 7) + (mt << 5) + (g << 3)) ^ swz] = pk.u;
      }
      lrow[sub] += psum;   // per-lane partial; no shuffle
    }

    // ---- PV: oacc += P(32x64) * V(64x64) ----
    __builtin_amdgcn_s_setprio(1);
#pragma unroll
    for (int kk = 0; kk < 2; ++kk)
#pragma unroll
      for (int sub = 0; sub < 2; ++sub) {
        // A-frag: P[ql][kk*32 + g*8 ..+8] -> byte ql*128 + kk*64 + g*16, swizzled
        bf16x8 pa = *(const bf16x8*)&P[w][sub][((ql << 7) + (kk << 6) + (g << 4)) ^ swz];
#pragma unroll
        for (int n = 0; n < 4; ++n)
          oacc[sub][n] = __builtin_amdgcn_mfma_f32_16x16x32_bf16(pa, vf[kk][n], oacc[sub][n], 0, 0, 0);
      }
    __builtin_amdgcn_s_setprio(0);
  }

  const int bo = bh >> 4, hh = bh & 15;
  bf16* Ob = O + (size_t)bo * S * D + hh * 64;
#pragma unroll
  for (int sub = 0; sub < 2; ++sub) {
    // reduce per-lane partial row sums across g groups (once per wave)
    float lr = lrow[sub];
    lr += __shfl_xor(lr, 16, 64);
    lr += __shfl_xor(lr, 32, 64);
    float ldv[4];
#pragma unroll
    for (int r = 0; r < 4; ++r) ldv[r] = __shfl(lr, g * 4 + r, 16);
#pragma unroll
    for (int r = 0; r < 4; ++r) {
      int qpos = qbase + sub * 16 + g * 4 + r;
      float inv = 1.f / ldv[r];
#pragma unroll
      for (int n = 0; n < 4; ++n)
        Ob[(size_t)qpos * D + n * 16 + ql] = __float2bfloat16(oacc[sub][n][r] * inv);
    }
  }
}

extern "C" void kernel_launch(void* const* d_in, const int* in_sizes, int n_in,
                              void* d_out, int out_size, void* d_ws, size_t ws_size,
                              hipStream_t stream) {
  const float* x  = (const float*)d_in[0];
  const float* wq = (const float*)d_in[1];
  const float* wk = (const float*)d_in[2];
  const float* wv = (const float*)d_in[3];
  const float* wo = (const float*)d_in[4];

  char* ws = (char*)d_ws;
  bf16* xb  = (bf16*)(ws);                      // 16 MB  [8192,1024]
  bf16* wqb = (bf16*)(ws + (16u << 20));        // 2 MB
  bf16* wkb = (bf16*)(ws + (18u << 20));
  bf16* wvb = (bf16*)(ws + (20u << 20));
  bf16* wob = (bf16*)(ws + (22u << 20));
  bf16* Qb  = (bf16*)(ws + (24u << 20));        // 16 MB [B,H,S,64] (pre-scaled)
  bf16* Kb  = (bf16*)(ws + (40u << 20));        // 16 MB [B,H,S,64]
  bf16* Vtb = (bf16*)(ws + (56u << 20));        // 16 MB [B,H,64,S]
  bf16* Ob  = (bf16*)(ws + (72u << 20));        // 16 MB [8192,1024]

  cvt_bf16_kernel<<<2048, 256, 0, stream>>>(x, xb, M * D);
  cvt_bf16_kernel<<<1024, 256, 0, stream>>>(wq, wqb, D * D);
  cvt_bf16_kernel<<<1024, 256, 0, stream>>>(wk, wkb, D * D);
  cvt_bf16_kernel<<<1024, 256, 0, stream>>>(wv, wvb, D * D);
  cvt_bf16_kernel<<<1024, 256, 0, stream>>>(wo, wob, D * D);

  // Q = x Wq^T (scaled 1/8), K = x Wk^T  -> [B,H,S,64]
  gemm_bt<0><<<dim3(M / 128, D / 128), 256, 0, stream>>>(xb, wqb, Qb, D, D, 0.125f);
  gemm_bt<0><<<dim3(M / 128, D / 128), 256, 0, stream>>>(xb, wkb, Kb, D, D, 1.0f);
  // Vt = Wv x^T -> [B,H,64,S]
  gemm_bt<1><<<dim3(D / 128, M / 128), 256, 0, stream>>>(wvb, xb, Vtb, D, D, 1.0f);

  attn_kernel<<<dim3(16, NB * NH), 256, 0, stream>>>(Qb, Kb, Vtb, Ob);

  // out = O Wo^T (fp32)
  gemm_bt<2><<<dim3(M / 128, D / 128), 256, 0, stream>>>(Ob, wob, d_out, D, D, 1.0f);
}